// Round 5
// baseline (538.570 us; speedup 1.0000x reference)
//
#include <hip/hip_runtime.h>
#include <cstdint>
#include <cstddef>

typedef __attribute__((ext_vector_type(8))) short short8;
typedef __attribute__((ext_vector_type(4))) float floatx4;

// Problem dims (fixed by the reference).
constexpr int MDIM = 32768;   // B
constexpr int DIN  = 1024;
constexpr int HDIM = 512;
constexpr int LDIM = 64;
constexpr uint32_t BL = (uint32_t)MDIM * (uint32_t)LDIM;  // 2097152

// ---------------------------------------------------------------------------
// Threefry2x32 (JAX-compatible, 20 rounds). Host+device.
// ---------------------------------------------------------------------------
__host__ __device__ __forceinline__ void tf2x32(uint32_t k0, uint32_t k1,
                                                uint32_t x0, uint32_t x1,
                                                uint32_t& o0, uint32_t& o1) {
  const uint32_t k2 = k0 ^ k1 ^ 0x1BD11BDAu;
  x0 += k0; x1 += k1;
#define TFR(r) { x0 += x1; x1 = (x1 << (r)) | (x1 >> (32 - (r))); x1 ^= x0; }
  TFR(13) TFR(15) TFR(26) TFR(6)
  x0 += k1; x1 += k2 + 1u;
  TFR(17) TFR(29) TFR(16) TFR(24)
  x0 += k2; x1 += k0 + 2u;
  TFR(13) TFR(15) TFR(26) TFR(6)
  x0 += k0; x1 += k1 + 3u;
  TFR(17) TFR(29) TFR(16) TFR(24)
  x0 += k1; x1 += k2 + 4u;
  TFR(13) TFR(15) TFR(26) TFR(6)
  x0 += k2; x1 += k0 + 5u;
#undef TFR
  o0 = x0; o1 = x1;
}

// jax_threefry_partitionable random_bits: element j -> counter (0, j), out0^out1.
__device__ __forceinline__ uint32_t tf_bits(uint32_t k0, uint32_t k1, uint32_t j) {
  uint32_t o0, o1;
  tf2x32(k0, k1, 0u, j, o0, o1);
  return o0 ^ o1;
}

// ---------------------------------------------------------------------------
// dtype helpers: f32 <-> bf16 bit tricks (RNE), and 3-way exact split.
// ---------------------------------------------------------------------------
__device__ __forceinline__ float b2f(unsigned short s) {
  return __uint_as_float((uint32_t)s << 16);
}
__device__ __forceinline__ unsigned short f2b(float f) {  // RNE f32 -> bf16
  uint32_t u = __float_as_uint(f);
  u += 0x7fffu + ((u >> 16) & 1u);
  return (unsigned short)(u >> 16);
}
// x = hi + lo + lo2 + r, |r| <= 2^-27 |x| (each subtraction exact).
__device__ __forceinline__ void split3(float x, unsigned short& h,
                                       unsigned short& l, unsigned short& l2) {
  h = f2b(x);
  const float r = __fsub_rn(x, b2f(h));
  l = f2b(r);
  const float r2 = __fsub_rn(r, b2f(l));
  l2 = f2b(r2);
}

// ---------------------------------------------------------------------------
// XLA-style Giles erfinv (f32), non-fused to match separate HLO mul/add.
// ---------------------------------------------------------------------------
__device__ __forceinline__ float erfinv_f32(float x) {
  const float xx = __fmul_rn(x, x);
  float w = -log1pf(-xx);
  float p;
  if (w < 5.0f) {
    w = __fadd_rn(w, -2.5f);
    p = 2.81022636e-08f;
    p = __fadd_rn(__fmul_rn(p, w), 3.43273939e-07f);
    p = __fadd_rn(__fmul_rn(p, w), -3.5233877e-06f);
    p = __fadd_rn(__fmul_rn(p, w), -4.39150654e-06f);
    p = __fadd_rn(__fmul_rn(p, w), 0.00021858087f);
    p = __fadd_rn(__fmul_rn(p, w), -0.00125372503f);
    p = __fadd_rn(__fmul_rn(p, w), -0.00417768164f);
    p = __fadd_rn(__fmul_rn(p, w), 0.246640727f);
    p = __fadd_rn(__fmul_rn(p, w), 1.50140941f);
  } else {
    w = __fadd_rn(sqrtf(w), -3.0f);
    p = -0.000200214257f;
    p = __fadd_rn(__fmul_rn(p, w), 0.000100950558f);
    p = __fadd_rn(__fmul_rn(p, w), 0.00134934322f);
    p = __fadd_rn(__fmul_rn(p, w), -0.00367342844f);
    p = __fadd_rn(__fmul_rn(p, w), 0.00573950773f);
    p = __fadd_rn(__fmul_rn(p, w), -0.0076224613f);
    p = __fadd_rn(__fmul_rn(p, w), 0.00943887047f);
    p = __fadd_rn(__fmul_rn(p, w), 1.00167406f);
    p = __fadd_rn(__fmul_rn(p, w), 2.83297682f);
  }
  return __fmul_rn(p, x);
}

#define LO_N  (-0x1.fffffep-1f)   /* -(1 - 2^-24) */
#define DIFF_N (2.0f)
#define SQRT2_F ((float)1.4142135623730951)
#define DIFF_U (0x1.fffffcp-1f)   /* f32(1.0f - 1e-7f) */
#define MINV_U (1e-7f)
#define THIRD_F ((float)(1.0 / 3.0))

// ---------------------------------------------------------------------------
// Marsaglia-Tsang sampler (JAX K=16 vectorized rejection, first accept).
// ---------------------------------------------------------------------------
__device__ float gamma_sample(float alpha, uint32_t e,
                              uint32_t kz0, uint32_t kz1,
                              uint32_t ku0, uint32_t ku1) {
  const float d = __fsub_rn(alpha, THIRD_F);
  const float c = __fdiv_rn(1.0f, sqrtf(__fmul_rn(9.0f, d)));
  float samp0 = 0.0f;
#pragma unroll 1
  for (int k = 0; k < 16; ++k) {
    const uint32_t j = (uint32_t)k * BL + e;
    const uint32_t zb = tf_bits(kz0, kz1, j);
    const uint32_t ub = tf_bits(ku0, ku1, j);
    const float fz = __fsub_rn(__uint_as_float((zb >> 9) | 0x3f800000u), 1.0f);
    float un = __fadd_rn(__fmul_rn(fz, DIFF_N), LO_N);
    un = fmaxf(un, LO_N);
    const float z = __fmul_rn(SQRT2_F, erfinv_f32(un));
    const float fu = __fsub_rn(__uint_as_float((ub >> 9) | 0x3f800000u), 1.0f);
    float uu = __fadd_rn(__fmul_rn(fu, DIFF_U), MINV_U);
    uu = fmaxf(uu, MINV_U);
    const float t1 = __fadd_rn(1.0f, __fmul_rn(c, z));
    const float v = __fmul_rn(t1, __fmul_rn(t1, t1));
    const bool pos = (v > 0.0f);
    const float sv = pos ? v : 1.0f;
    const float b2 = __fadd_rn(
        __fsub_rn(__fadd_rn(__fmul_rn(0.5f, __fmul_rn(z, z)), d),
                  __fmul_rn(d, sv)),
        __fmul_rn(d, logf(sv)));
    const float lu = logf(uu);
    const float s = __fmul_rn(d, sv);
    if (k == 0) samp0 = s;
    if (pos && (lu < b2)) return s;
  }
  return samp0;
}

// ---------------------------------------------------------------------------
// Prep: split W[K][N] (f32) into 3 bf16 planes, TRANSPOSED to [N][K].
// 32x32 tiles via LDS. Planes at D + p*N*K.
// ---------------------------------------------------------------------------
__global__ __launch_bounds__(256) void split_transpose(
    const float* __restrict__ W, unsigned short* __restrict__ D, int K, int N) {
  __shared__ unsigned short th[32][33], tl[32][33], tl2[32][33];
  const int t = threadIdx.x;
  const int nb = N / 32;
  const int k0 = (blockIdx.x / nb) * 32, n0 = (blockIdx.x % nb) * 32;
#pragma unroll
  for (int i = 0; i < 4; ++i) {
    const int e = i * 256 + t;
    const int kk = e >> 5, nn = e & 31;
    const float x = W[(size_t)(k0 + kk) * N + (n0 + nn)];
    split3(x, th[kk][nn], tl[kk][nn], tl2[kk][nn]);
  }
  __syncthreads();
  const size_t PL = (size_t)N * K;
#pragma unroll
  for (int i = 0; i < 4; ++i) {
    const int e = i * 256 + t;
    const int nn = e >> 5, kk = e & 31;
    const size_t o = (size_t)(n0 + nn) * K + (k0 + kk);
    D[o] = th[kk][nn];
    D[PL + o] = tl[kk][nn];
    D[2 * PL + o] = tl2[kk][nn];
  }
}

// ---------------------------------------------------------------------------
// Split-bf16 MFMA GEMM body.  C[M,512] = relu(A[M,K] @ B[K,512] + b)
// r1-proven 2-barrier structure, scaled to BM=256 x BN=128, 8 waves:
//   - LDS 72KB (As 48 + Bs 24) -> 2 blocks/CU = 16 waves/CU (was 12).
//   - B-staging per CU halved vs 128x128 (BN panel shared by 2x rows).
//   - Per-wave inner work unchanged: 96 MFMA, 24 ds_read_b128 per K-step.
// No XCD swizzle: measured +10us cost at r4 (L3-resident working set).
// XOR bank-swizzle on both LDS tiles (conflicts measured 0).
// ---------------------------------------------------------------------------
template <int K>
__device__ __forceinline__ void gemm_body(
    const float* __restrict__ A, const unsigned short* __restrict__ BT,
    const float* __restrict__ bias, float* __restrict__ C) {
  constexpr int N = 512;
  constexpr size_t PL = (size_t)N * K;
  __shared__ unsigned short As[3][256 * 32];   // 48 KB
  __shared__ unsigned short Bs[3][128 * 32];   // 24 KB
  const int t = threadIdx.x;
  const int lane = t & 63, w = t >> 6;         // 8 waves
  const int wm = w >> 1, wn = w & 1;           // 4x2 wave grid (64x64 tiles)
  const int ln = lane & 15, kq = lane >> 4;
  const int bm = blockIdx.y * 256, bn = blockIdx.x * 128;
  const int rq = kq ^ ((ln >> 1) & 3);                      // read granule slot
  const int kcs = ((lane & 3) ^ ((lane >> 3) & 3)) * 8;     // B-source permute

  floatx4 acc[4][4];
#pragma unroll
  for (int i = 0; i < 4; ++i)
#pragma unroll
    for (int j = 0; j < 4; ++j) acc[i][j] = (floatx4)0.0f;

  for (int k0 = 0; k0 < K; k0 += 32) {
    // ---- B staging: wave w stages rows w*16..w*16+15 per plane ----
#pragma unroll
    for (int p = 0; p < 3; ++p) {
      const int n = w * 16 + (lane >> 2);
      const unsigned short* g = BT + p * PL + (size_t)(bn + n) * K + (k0 + kcs);
      __builtin_amdgcn_global_load_lds(
          (const __attribute__((address_space(1))) unsigned int*)g,
          (__attribute__((address_space(3))) unsigned int*)&Bs[p][w * 512],
          16, 0, 0);
    }
    // ---- A staging: 256x32 f32 tile, 4 float4/thread + 3-way split ----
#pragma unroll
    for (int it = 0; it < 4; ++it) {
      const int e4 = (it * 512 + t) * 4;
      const int m = e4 >> 5, kc = e4 & 31;
      const float4 q = *reinterpret_cast<const float4*>(
          &A[(size_t)(bm + m) * K + (k0 + kc)]);
      ushort4 h, l, l2;
      split3(q.x, h.x, l.x, l2.x);
      split3(q.y, h.y, l.y, l2.y);
      split3(q.z, h.z, l.z, l2.z);
      split3(q.w, h.w, l.w, l2.w);
      const int si = m * 32 + (((kc >> 3) ^ ((m >> 1) & 3)) << 3) + (kc & 7);
      *reinterpret_cast<ushort4*>(&As[0][si]) = h;
      *reinterpret_cast<ushort4*>(&As[1][si]) = l;
      *reinterpret_cast<ushort4*>(&As[2][si]) = l2;
    }
    __syncthreads();
    // ---- fragments (swizzled slot read) ----
    short8 af[3][4], bf[3][4];
#pragma unroll
    for (int mi = 0; mi < 4; ++mi)
#pragma unroll
      for (int p = 0; p < 3; ++p)
        af[p][mi] = *reinterpret_cast<const short8*>(
            &As[p][(wm * 64 + mi * 16 + ln) * 32 + rq * 8]);
#pragma unroll
    for (int ni = 0; ni < 4; ++ni)
#pragma unroll
      for (int p = 0; p < 3; ++p)
        bf[p][ni] = *reinterpret_cast<const short8*>(
            &Bs[p][(wn * 64 + ni * 16 + ln) * 32 + rq * 8]);
    // ---- 6-term MFMA ----
#pragma unroll
    for (int mi = 0; mi < 4; ++mi)
#pragma unroll
      for (int ni = 0; ni < 4; ++ni) {
        floatx4 a = acc[mi][ni];
        a = __builtin_amdgcn_mfma_f32_16x16x32_bf16(af[0][mi], bf[0][ni], a, 0, 0, 0);
        a = __builtin_amdgcn_mfma_f32_16x16x32_bf16(af[0][mi], bf[1][ni], a, 0, 0, 0);
        a = __builtin_amdgcn_mfma_f32_16x16x32_bf16(af[1][mi], bf[0][ni], a, 0, 0, 0);
        a = __builtin_amdgcn_mfma_f32_16x16x32_bf16(af[1][mi], bf[1][ni], a, 0, 0, 0);
        a = __builtin_amdgcn_mfma_f32_16x16x32_bf16(af[0][mi], bf[2][ni], a, 0, 0, 0);
        a = __builtin_amdgcn_mfma_f32_16x16x32_bf16(af[2][mi], bf[0][ni], a, 0, 0, 0);
        acc[mi][ni] = a;
      }
    __syncthreads();
  }
  // ---- epilogue: bias + ReLU, C/D layout row=kq*4+r, col=ln ----
#pragma unroll
  for (int ni = 0; ni < 4; ++ni) {
    const int n = bn + wn * 64 + ni * 16 + ln;
    const float bb = bias[n];
#pragma unroll
    for (int mi = 0; mi < 4; ++mi)
#pragma unroll
      for (int r = 0; r < 4; ++r) {
        const int m = bm + wm * 64 + mi * 16 + kq * 4 + r;
        C[(size_t)m * N + n] = fmaxf(__fadd_rn(acc[mi][ni][r], bb), 0.0f);
      }
  }
}

// Distinct symbols per layer so rocprof rows attribute cleanly.
__global__ __launch_bounds__(512, 4) void gemm1_k1024(
    const float* __restrict__ A, const unsigned short* __restrict__ BT,
    const float* __restrict__ bias, float* __restrict__ C) {
  gemm_body<DIN>(A, BT, bias, C);
}
__global__ __launch_bounds__(512, 4) void gemm2_k512(
    const float* __restrict__ A, const unsigned short* __restrict__ BT,
    const float* __restrict__ bias, float* __restrict__ C) {
  gemm_body<HDIM>(A, BT, bias, C);
}

// ---------------------------------------------------------------------------
// Layer 3 split-bf16 MFMA + softplus: ALPHA ONLY. 8 waves (512 threads),
// r1-proven structure: BM=64, N=64, K=512. Wave w: rows (w>>1)*16, col half
// (w&1)*32 -> acc[2]. 512 blocks = 2/CU x 8 waves = 16 waves/CU.
// ---------------------------------------------------------------------------
__global__ __launch_bounds__(512, 4) void gemm3_alpha(
    const float* __restrict__ A, const unsigned short* __restrict__ BT,
    const float* __restrict__ bl, float* __restrict__ out) {
  constexpr int K = 512, N = 64;
  constexpr size_t PL = (size_t)N * K;  // 32768
  __shared__ unsigned short As[3][64 * 32];
  __shared__ unsigned short Bs[3][64 * 32];
  const int t = threadIdx.x;
  const int lane = t & 63, w = t >> 6;   // 8 waves
  const int wm = w >> 1, wn = w & 1;
  const int ln = lane & 15, kq = lane >> 4;
  const int bm = blockIdx.x * 64;
  const int rq = kq ^ ((ln >> 1) & 3);
  const int kcs = ((lane & 3) ^ ((lane >> 3) & 3)) * 8;
  const int arow = t >> 3, acol = (t * 4) & 31;  // 512 thr x float4 = 64x32
  const int swz = ((((acol >> 3) ^ ((arow >> 1) & 3)) << 3) | (acol & 7));

  floatx4 acc[2];
  acc[0] = (floatx4)0.0f;
  acc[1] = (floatx4)0.0f;

  for (int k0 = 0; k0 < K; k0 += 32) {
    // ---- B staging: 12 wave-segments (3 planes x 4 x 16-row chunks) ----
    for (int s2 = w; s2 < 12; s2 += 8) {
      const int p = s2 >> 2, half = s2 & 3;
      const int n = half * 16 + (lane >> 2);
      const unsigned short* g = BT + p * PL + (size_t)n * K + (k0 + kcs);
      __builtin_amdgcn_global_load_lds(
          (const __attribute__((address_space(1))) unsigned int*)g,
          (__attribute__((address_space(3))) unsigned int*)&Bs[p][half * 512],
          16, 0, 0);
    }
    // ---- A staging: one float4/thread + 3-way split ----
    {
      const float4 q = *reinterpret_cast<const float4*>(
          &A[(size_t)(bm + arow) * K + (k0 + acol)]);
      ushort4 h, l, l2;
      split3(q.x, h.x, l.x, l2.x);
      split3(q.y, h.y, l.y, l2.y);
      split3(q.z, h.z, l.z, l2.z);
      split3(q.w, h.w, l.w, l2.w);
      const int si = arow * 32 + swz;
      *reinterpret_cast<ushort4*>(&As[0][si]) = h;
      *reinterpret_cast<ushort4*>(&As[1][si]) = l;
      *reinterpret_cast<ushort4*>(&As[2][si]) = l2;
    }
    __syncthreads();
    short8 af[3], bf[3][2];
#pragma unroll
    for (int p = 0; p < 3; ++p)
      af[p] = *reinterpret_cast<const short8*>(
          &As[p][(wm * 16 + ln) * 32 + rq * 8]);
#pragma unroll
    for (int j = 0; j < 2; ++j)
#pragma unroll
      for (int p = 0; p < 3; ++p)
        bf[p][j] = *reinterpret_cast<const short8*>(
            &Bs[p][(wn * 32 + j * 16 + ln) * 32 + rq * 8]);
#pragma unroll
    for (int j = 0; j < 2; ++j) {
      floatx4 a = acc[j];
      a = __builtin_amdgcn_mfma_f32_16x16x32_bf16(af[0], bf[0][j], a, 0, 0, 0);
      a = __builtin_amdgcn_mfma_f32_16x16x32_bf16(af[0], bf[1][j], a, 0, 0, 0);
      a = __builtin_amdgcn_mfma_f32_16x16x32_bf16(af[1], bf[0][j], a, 0, 0, 0);
      a = __builtin_amdgcn_mfma_f32_16x16x32_bf16(af[1], bf[1][j], a, 0, 0, 0);
      a = __builtin_amdgcn_mfma_f32_16x16x32_bf16(af[0], bf[2][j], a, 0, 0, 0);
      a = __builtin_amdgcn_mfma_f32_16x16x32_bf16(af[2], bf[0][j], a, 0, 0, 0);
      acc[j] = a;
    }
    __syncthreads();
  }
  // ---- epilogue: bias + softplus + 0.5 -> alpha only ----
#pragma unroll
  for (int j = 0; j < 2; ++j) {
    const int n = wn * 32 + j * 16 + ln;
    const float bb = bl[n];
#pragma unroll
    for (int r = 0; r < 4; ++r) {
      const int m = bm + wm * 16 + kq * 4 + r;
      const float x = __fadd_rn(acc[j][r], bb);
      const float sp = __fadd_rn(fmaxf(x, 0.0f), log1pf(expf(-fabsf(x))));
      out[(size_t)m * 64 + n] = __fadd_rn(sp, 0.5f);
    }
  }
}

// ---------------------------------------------------------------------------
// Standalone gamma sampler: 2M elements, 4 per thread, float4 coalesced.
// Minimal VGPR -> high occupancy; rejection-loop divergence hides under TLP.
// ---------------------------------------------------------------------------
__global__ __launch_bounds__(256) void gamma_kernel(
    const float* __restrict__ alpha, float* __restrict__ smp,
    uint32_t kz0, uint32_t kz1, uint32_t ku0, uint32_t ku1) {
  const uint32_t i4 = ((uint32_t)blockIdx.x * 256u + (uint32_t)threadIdx.x) * 4u;
  const float4 a = *reinterpret_cast<const float4*>(&alpha[i4]);
  float4 s;
  s.x = gamma_sample(a.x, i4 + 0u, kz0, kz1, ku0, ku1);
  s.y = gamma_sample(a.y, i4 + 1u, kz0, kz1, ku0, ku1);
  s.z = gamma_sample(a.z, i4 + 2u, kz0, kz1, ku0, ku1);
  s.w = gamma_sample(a.w, i4 + 3u, kz0, kz1, ku0, ku1);
  *reinterpret_cast<float4*>(&smp[i4]) = s;
}

// ---------------------------------------------------------------------------
extern "C" void kernel_launch(void* const* d_in, const int* in_sizes, int n_in,
                              void* d_out, int out_size, void* d_ws, size_t ws_size,
                              hipStream_t stream) {
  (void)in_sizes; (void)n_in; (void)out_size; (void)ws_size;
  const float* x  = (const float*)d_in[0];
  const float* W0 = (const float*)d_in[1];
  const float* b0 = (const float*)d_in[2];
  const float* W1 = (const float*)d_in[3];
  const float* b1 = (const float*)d_in[4];
  const float* Wl = (const float*)d_in[5];
  const float* bl = (const float*)d_in[6];
  float* h1 = (float*)d_ws;                      // 32768x512 f32 = 64 MiB
  float* h2 = h1 + (size_t)MDIM * HDIM;          // 64 MiB
  float* out = (float*)d_out;                    // [alpha | sample], f32

  // d_out doubles as early scratch for the pre-split transposed W planes
  // (consumed by gemm1/gemm2, then overwritten by gemm3_alpha/gamma_kernel).
  unsigned short* W0T = (unsigned short*)out;           // 3 MiB in alpha region
  unsigned short* W1T = (unsigned short*)(out + BL);    // 1.5 MiB in sample region
  // WlT goes into the h1 region AFTER gemm2 has consumed h1 (stream-ordered).
  unsigned short* WlT = (unsigned short*)d_ws;          // 192 KiB, dead-h1 reuse

  // jax.random.split(jax.random.key(1)) under jax_threefry_partitionable.
  uint32_t kz0, kz1, ku0, ku1;
  tf2x32(0u, 1u, 0u, 0u, kz0, kz1);
  tf2x32(0u, 1u, 0u, 1u, ku0, ku1);

  split_transpose<<<dim3((DIN / 32) * (HDIM / 32)), 256, 0, stream>>>(
      W0, W0T, DIN, HDIM);
  split_transpose<<<dim3((HDIM / 32) * (HDIM / 32)), 256, 0, stream>>>(
      W1, W1T, HDIM, HDIM);

  dim3 g12(HDIM / 128, MDIM / 256);  // (4, 128) = 512 blocks
  gemm1_k1024<<<g12, 512, 0, stream>>>(x, W0T, b0, h1);
  gemm2_k512<<<g12, 512, 0, stream>>>(h1, W1T, b1, h2);

  split_transpose<<<dim3((HDIM / 32) * (LDIM / 32)), 256, 0, stream>>>(
      Wl, WlT, HDIM, LDIM);

  gemm3_alpha<<<dim3(MDIM / 64), 512, 0, stream>>>(h2, WlT, bl, out);

  // alpha region of d_out is complete; sample from it.
  gamma_kernel<<<dim3(BL / 1024), 256, 0, stream>>>(out, out + BL,
                                                    kz0, kz1, ku0, ku1);
}

// Round 6
// 506.440 us; speedup vs baseline: 1.0634x; 1.0634x over previous
//
#include <hip/hip_runtime.h>
#include <cstdint>
#include <cstddef>

typedef __attribute__((ext_vector_type(8))) short short8;
typedef __attribute__((ext_vector_type(4))) float floatx4;

// Problem dims (fixed by the reference).
constexpr int MDIM = 32768;   // B
constexpr int DIN  = 1024;
constexpr int HDIM = 512;
constexpr int LDIM = 64;
constexpr uint32_t BL = (uint32_t)MDIM * (uint32_t)LDIM;  // 2097152

// ---------------------------------------------------------------------------
// Threefry2x32 (JAX-compatible, 20 rounds). Host+device.
// ---------------------------------------------------------------------------
__host__ __device__ __forceinline__ void tf2x32(uint32_t k0, uint32_t k1,
                                                uint32_t x0, uint32_t x1,
                                                uint32_t& o0, uint32_t& o1) {
  const uint32_t k2 = k0 ^ k1 ^ 0x1BD11BDAu;
  x0 += k0; x1 += k1;
#define TFR(r) { x0 += x1; x1 = (x1 << (r)) | (x1 >> (32 - (r))); x1 ^= x0; }
  TFR(13) TFR(15) TFR(26) TFR(6)
  x0 += k1; x1 += k2 + 1u;
  TFR(17) TFR(29) TFR(16) TFR(24)
  x0 += k2; x1 += k0 + 2u;
  TFR(13) TFR(15) TFR(26) TFR(6)
  x0 += k0; x1 += k1 + 3u;
  TFR(17) TFR(29) TFR(16) TFR(24)
  x0 += k1; x1 += k2 + 4u;
  TFR(13) TFR(15) TFR(26) TFR(6)
  x0 += k2; x1 += k0 + 5u;
#undef TFR
  o0 = x0; o1 = x1;
}

// jax_threefry_partitionable random_bits: element j -> counter (0, j), out0^out1.
__device__ __forceinline__ uint32_t tf_bits(uint32_t k0, uint32_t k1, uint32_t j) {
  uint32_t o0, o1;
  tf2x32(k0, k1, 0u, j, o0, o1);
  return o0 ^ o1;
}

// ---------------------------------------------------------------------------
// dtype helpers: f32 <-> bf16 bit tricks (RNE), and 3-way exact split.
// ---------------------------------------------------------------------------
__device__ __forceinline__ float b2f(unsigned short s) {
  return __uint_as_float((uint32_t)s << 16);
}
__device__ __forceinline__ unsigned short f2b(float f) {  // RNE f32 -> bf16
  uint32_t u = __float_as_uint(f);
  u += 0x7fffu + ((u >> 16) & 1u);
  return (unsigned short)(u >> 16);
}
// x = hi + lo + lo2 + r, |r| <= 2^-27 |x| (each subtraction exact).
__device__ __forceinline__ void split3(float x, unsigned short& h,
                                       unsigned short& l, unsigned short& l2) {
  h = f2b(x);
  const float r = __fsub_rn(x, b2f(h));
  l = f2b(r);
  const float r2 = __fsub_rn(r, b2f(l));
  l2 = f2b(r2);
}

// ---------------------------------------------------------------------------
// XLA-style Giles erfinv (f32), non-fused to match separate HLO mul/add.
// ---------------------------------------------------------------------------
__device__ __forceinline__ float erfinv_f32(float x) {
  const float xx = __fmul_rn(x, x);
  float w = -log1pf(-xx);
  float p;
  if (w < 5.0f) {
    w = __fadd_rn(w, -2.5f);
    p = 2.81022636e-08f;
    p = __fadd_rn(__fmul_rn(p, w), 3.43273939e-07f);
    p = __fadd_rn(__fmul_rn(p, w), -3.5233877e-06f);
    p = __fadd_rn(__fmul_rn(p, w), -4.39150654e-06f);
    p = __fadd_rn(__fmul_rn(p, w), 0.00021858087f);
    p = __fadd_rn(__fmul_rn(p, w), -0.00125372503f);
    p = __fadd_rn(__fmul_rn(p, w), -0.00417768164f);
    p = __fadd_rn(__fmul_rn(p, w), 0.246640727f);
    p = __fadd_rn(__fmul_rn(p, w), 1.50140941f);
  } else {
    w = __fadd_rn(sqrtf(w), -3.0f);
    p = -0.000200214257f;
    p = __fadd_rn(__fmul_rn(p, w), 0.000100950558f);
    p = __fadd_rn(__fmul_rn(p, w), 0.00134934322f);
    p = __fadd_rn(__fmul_rn(p, w), -0.00367342844f);
    p = __fadd_rn(__fmul_rn(p, w), 0.00573950773f);
    p = __fadd_rn(__fmul_rn(p, w), -0.0076224613f);
    p = __fadd_rn(__fmul_rn(p, w), 0.00943887047f);
    p = __fadd_rn(__fmul_rn(p, w), 1.00167406f);
    p = __fadd_rn(__fmul_rn(p, w), 2.83297682f);
  }
  return __fmul_rn(p, x);
}

#define LO_N  (-0x1.fffffep-1f)   /* -(1 - 2^-24) */
#define DIFF_N (2.0f)
#define SQRT2_F ((float)1.4142135623730951)
#define DIFF_U (0x1.fffffcp-1f)   /* f32(1.0f - 1e-7f) */
#define MINV_U (1e-7f)
#define THIRD_F ((float)(1.0 / 3.0))

// ---------------------------------------------------------------------------
// Marsaglia-Tsang sampler (JAX K=16 vectorized rejection, first accept).
// ---------------------------------------------------------------------------
__device__ float gamma_sample(float alpha, uint32_t e,
                              uint32_t kz0, uint32_t kz1,
                              uint32_t ku0, uint32_t ku1) {
  const float d = __fsub_rn(alpha, THIRD_F);
  const float c = __fdiv_rn(1.0f, sqrtf(__fmul_rn(9.0f, d)));
  float samp0 = 0.0f;
#pragma unroll 1
  for (int k = 0; k < 16; ++k) {
    const uint32_t j = (uint32_t)k * BL + e;
    const uint32_t zb = tf_bits(kz0, kz1, j);
    const uint32_t ub = tf_bits(ku0, ku1, j);
    const float fz = __fsub_rn(__uint_as_float((zb >> 9) | 0x3f800000u), 1.0f);
    float un = __fadd_rn(__fmul_rn(fz, DIFF_N), LO_N);
    un = fmaxf(un, LO_N);
    const float z = __fmul_rn(SQRT2_F, erfinv_f32(un));
    const float fu = __fsub_rn(__uint_as_float((ub >> 9) | 0x3f800000u), 1.0f);
    float uu = __fadd_rn(__fmul_rn(fu, DIFF_U), MINV_U);
    uu = fmaxf(uu, MINV_U);
    const float t1 = __fadd_rn(1.0f, __fmul_rn(c, z));
    const float v = __fmul_rn(t1, __fmul_rn(t1, t1));
    const bool pos = (v > 0.0f);
    const float sv = pos ? v : 1.0f;
    const float b2 = __fadd_rn(
        __fsub_rn(__fadd_rn(__fmul_rn(0.5f, __fmul_rn(z, z)), d),
                  __fmul_rn(d, sv)),
        __fmul_rn(d, logf(sv)));
    const float lu = logf(uu);
    const float s = __fmul_rn(d, sv);
    if (k == 0) samp0 = s;
    if (pos && (lu < b2)) return s;
  }
  return samp0;
}

// ---------------------------------------------------------------------------
// Prep: split W[K][N] (f32) into 3 bf16 planes, TRANSPOSED to [N][K].
// 32x32 tiles via LDS. Planes at D + p*N*K.
// ---------------------------------------------------------------------------
__global__ __launch_bounds__(256) void split_transpose(
    const float* __restrict__ W, unsigned short* __restrict__ D, int K, int N) {
  __shared__ unsigned short th[32][33], tl[32][33], tl2[32][33];
  const int t = threadIdx.x;
  const int nb = N / 32;
  const int k0 = (blockIdx.x / nb) * 32, n0 = (blockIdx.x % nb) * 32;
#pragma unroll
  for (int i = 0; i < 4; ++i) {
    const int e = i * 256 + t;
    const int kk = e >> 5, nn = e & 31;
    const float x = W[(size_t)(k0 + kk) * N + (n0 + nn)];
    split3(x, th[kk][nn], tl[kk][nn], tl2[kk][nn]);
  }
  __syncthreads();
  const size_t PL = (size_t)N * K;
#pragma unroll
  for (int i = 0; i < 4; ++i) {
    const int e = i * 256 + t;
    const int nn = e >> 5, kk = e & 31;
    const size_t o = (size_t)(n0 + nn) * K + (k0 + kk);
    D[o] = th[kk][nn];
    D[PL + o] = tl[kk][nn];
    D[2 * PL + o] = tl2[kk][nn];
  }
}

// ---------------------------------------------------------------------------
// G1: EXACT r1-proven kernel (203 us). BM=BN=128, 4 waves, 48 KB LDS,
// 3 blocks/CU, two barriers per K-step, no XCD swizzle (r4: swizzle cost
// +10us, L3-resident working set). XOR bank-swizzle (conflicts measured 0).
// ---------------------------------------------------------------------------
__global__ __launch_bounds__(256) void gemm1_k1024(
    const float* __restrict__ A, const unsigned short* __restrict__ BT,
    const float* __restrict__ bias, float* __restrict__ C) {
  constexpr int K = DIN;            // 1024
  constexpr int N = 512;
  constexpr size_t PL = (size_t)N * K;
  __shared__ unsigned short As[3][128 * 32];
  __shared__ unsigned short Bs[3][128 * 32];
  const int t = threadIdx.x;
  const int lane = t & 63, w = t >> 6;
  const int wm = w >> 1, wn = w & 1;
  const int ln = lane & 15, kq = lane >> 4;
  const int bm = blockIdx.y * 128, bn = blockIdx.x * 128;
  const int rq = kq ^ ((ln >> 1) & 3);                      // read granule slot
  const int kcs = ((lane & 3) ^ ((lane >> 3) & 3)) * 8;     // B-source permute

  floatx4 acc[4][4];
#pragma unroll
  for (int i = 0; i < 4; ++i)
#pragma unroll
    for (int j = 0; j < 4; ++j) acc[i][j] = (floatx4)0.0f;

  for (int k0 = 0; k0 < K; k0 += 32) {
    // ---- B staging: async 16B direct-to-LDS, source-permuted k granule ----
#pragma unroll
    for (int p = 0; p < 3; ++p)
#pragma unroll
      for (int i = 0; i < 2; ++i) {
        const int e = w * 1024 + i * 512 + lane * 8;  // ushort idx in 128x32 tile
        const int n = e >> 5;
        const unsigned short* g = BT + p * PL + (size_t)(bn + n) * K + (k0 + kcs);
        __builtin_amdgcn_global_load_lds(
            (const __attribute__((address_space(1))) unsigned int*)g,
            (__attribute__((address_space(3))) unsigned int*)&Bs[p][w * 1024 + i * 512],
            16, 0, 0);
      }
    // ---- A staging: f32 load + 3-way split, swizzled store slot ----
#pragma unroll
    for (int it = 0; it < 4; ++it) {
      const int e4 = (it * 256 + t) * 4;
      const int m = e4 >> 5, kc = e4 & 31;
      const float4 q = *reinterpret_cast<const float4*>(
          &A[(size_t)(bm + m) * K + (k0 + kc)]);
      ushort4 h, l, l2;
      split3(q.x, h.x, l.x, l2.x);
      split3(q.y, h.y, l.y, l2.y);
      split3(q.z, h.z, l.z, l2.z);
      split3(q.w, h.w, l.w, l2.w);
      const int si = m * 32 + (((kc >> 3) ^ ((m >> 1) & 3)) << 3) + (kc & 7);
      *reinterpret_cast<ushort4*>(&As[0][si]) = h;
      *reinterpret_cast<ushort4*>(&As[1][si]) = l;
      *reinterpret_cast<ushort4*>(&As[2][si]) = l2;
    }
    __syncthreads();
    // ---- fragments (swizzled slot read) ----
    short8 af[3][4], bf[3][4];
#pragma unroll
    for (int mi = 0; mi < 4; ++mi)
#pragma unroll
      for (int p = 0; p < 3; ++p)
        af[p][mi] = *reinterpret_cast<const short8*>(
            &As[p][(wm * 64 + mi * 16 + ln) * 32 + rq * 8]);
#pragma unroll
    for (int ni = 0; ni < 4; ++ni)
#pragma unroll
      for (int p = 0; p < 3; ++p)
        bf[p][ni] = *reinterpret_cast<const short8*>(
            &Bs[p][(wn * 64 + ni * 16 + ln) * 32 + rq * 8]);
    // ---- 6-term MFMA ----
#pragma unroll
    for (int mi = 0; mi < 4; ++mi)
#pragma unroll
      for (int ni = 0; ni < 4; ++ni) {
        floatx4 a = acc[mi][ni];
        a = __builtin_amdgcn_mfma_f32_16x16x32_bf16(af[0][mi], bf[0][ni], a, 0, 0, 0);
        a = __builtin_amdgcn_mfma_f32_16x16x32_bf16(af[0][mi], bf[1][ni], a, 0, 0, 0);
        a = __builtin_amdgcn_mfma_f32_16x16x32_bf16(af[1][mi], bf[0][ni], a, 0, 0, 0);
        a = __builtin_amdgcn_mfma_f32_16x16x32_bf16(af[1][mi], bf[1][ni], a, 0, 0, 0);
        a = __builtin_amdgcn_mfma_f32_16x16x32_bf16(af[0][mi], bf[2][ni], a, 0, 0, 0);
        a = __builtin_amdgcn_mfma_f32_16x16x32_bf16(af[2][mi], bf[0][ni], a, 0, 0, 0);
        acc[mi][ni] = a;
      }
    __syncthreads();
  }
  // ---- epilogue: bias + ReLU, C/D layout row=kq*4+r, col=ln ----
#pragma unroll
  for (int ni = 0; ni < 4; ++ni) {
    const int n = bn + wn * 64 + ni * 16 + ln;
    const float bb = bias[n];
#pragma unroll
    for (int mi = 0; mi < 4; ++mi)
#pragma unroll
      for (int r = 0; r < 4; ++r) {
        const int m = bm + wm * 64 + mi * 16 + kq * 4 + r;
        C[(size_t)m * N + n] = fmaxf(__fadd_rn(acc[mi][ni][r], bb), 0.0f);
      }
  }
}

// ---------------------------------------------------------------------------
// G2: same proven 2-barrier structure, BM=64 x BN=128 (TLP experiment).
// Evidence: G2 has run ~= G1 (~205us) every round despite half the K-steps
// (r0 ords 26/28 both ~206; totals only reconcile with G2~G1) -> G2 is
// latency-bound, not FLOP-bound. This shape: LDS 36KB -> 4 blocks/CU =
// 16 waves/CU (vs 12), acc 32 VGPR (vs 64), 2048 blocks -> 4 independent
// barrier-pipelines per CU to overlap staging latency.
// Per-output accumulation chain bit-identical to r1's G2.
// ---------------------------------------------------------------------------
__global__ __launch_bounds__(256) void gemm2_k512(
    const float* __restrict__ A, const unsigned short* __restrict__ BT,
    const float* __restrict__ bias, float* __restrict__ C) {
  constexpr int K = HDIM;           // 512
  constexpr int N = 512;
  constexpr size_t PL = (size_t)N * K;
  __shared__ unsigned short As[3][64 * 32];    // 12 KB
  __shared__ unsigned short Bs[3][128 * 32];   // 24 KB
  const int t = threadIdx.x;
  const int lane = t & 63, w = t >> 6;
  const int wm = w >> 1, wn = w & 1;           // 2x2 wave grid, 32x64 each
  const int ln = lane & 15, kq = lane >> 4;
  const int bm = blockIdx.y * 64, bn = blockIdx.x * 128;
  const int rq = kq ^ ((ln >> 1) & 3);
  const int kcs = ((lane & 3) ^ ((lane >> 3) & 3)) * 8;

  floatx4 acc[2][4];
#pragma unroll
  for (int i = 0; i < 2; ++i)
#pragma unroll
    for (int j = 0; j < 4; ++j) acc[i][j] = (floatx4)0.0f;

  for (int k0 = 0; k0 < K; k0 += 32) {
    // ---- B staging: identical pattern to G1 (128x32 tile, 3 planes) ----
#pragma unroll
    for (int p = 0; p < 3; ++p)
#pragma unroll
      for (int i = 0; i < 2; ++i) {
        const int e = w * 1024 + i * 512 + lane * 8;
        const int n = e >> 5;
        const unsigned short* g = BT + p * PL + (size_t)(bn + n) * K + (k0 + kcs);
        __builtin_amdgcn_global_load_lds(
            (const __attribute__((address_space(1))) unsigned int*)g,
            (__attribute__((address_space(3))) unsigned int*)&Bs[p][w * 1024 + i * 512],
            16, 0, 0);
      }
    // ---- A staging: 64x32 tile, 2 float4/thread + 3-way split ----
#pragma unroll
    for (int it = 0; it < 2; ++it) {
      const int e4 = (it * 256 + t) * 4;
      const int m = e4 >> 5, kc = e4 & 31;
      const float4 q = *reinterpret_cast<const float4*>(
          &A[(size_t)(bm + m) * K + (k0 + kc)]);
      ushort4 h, l, l2;
      split3(q.x, h.x, l.x, l2.x);
      split3(q.y, h.y, l.y, l2.y);
      split3(q.z, h.z, l.z, l2.z);
      split3(q.w, h.w, l.w, l2.w);
      const int si = m * 32 + (((kc >> 3) ^ ((m >> 1) & 3)) << 3) + (kc & 7);
      *reinterpret_cast<ushort4*>(&As[0][si]) = h;
      *reinterpret_cast<ushort4*>(&As[1][si]) = l;
      *reinterpret_cast<ushort4*>(&As[2][si]) = l2;
    }
    __syncthreads();
    // ---- fragments ----
    short8 af[3][2], bf[3][4];
#pragma unroll
    for (int mi = 0; mi < 2; ++mi)
#pragma unroll
      for (int p = 0; p < 3; ++p)
        af[p][mi] = *reinterpret_cast<const short8*>(
            &As[p][(wm * 32 + mi * 16 + ln) * 32 + rq * 8]);
#pragma unroll
    for (int ni = 0; ni < 4; ++ni)
#pragma unroll
      for (int p = 0; p < 3; ++p)
        bf[p][ni] = *reinterpret_cast<const short8*>(
            &Bs[p][(wn * 64 + ni * 16 + ln) * 32 + rq * 8]);
    // ---- 6-term MFMA ----
#pragma unroll
    for (int mi = 0; mi < 2; ++mi)
#pragma unroll
      for (int ni = 0; ni < 4; ++ni) {
        floatx4 a = acc[mi][ni];
        a = __builtin_amdgcn_mfma_f32_16x16x32_bf16(af[0][mi], bf[0][ni], a, 0, 0, 0);
        a = __builtin_amdgcn_mfma_f32_16x16x32_bf16(af[0][mi], bf[1][ni], a, 0, 0, 0);
        a = __builtin_amdgcn_mfma_f32_16x16x32_bf16(af[1][mi], bf[0][ni], a, 0, 0, 0);
        a = __builtin_amdgcn_mfma_f32_16x16x32_bf16(af[1][mi], bf[1][ni], a, 0, 0, 0);
        a = __builtin_amdgcn_mfma_f32_16x16x32_bf16(af[0][mi], bf[2][ni], a, 0, 0, 0);
        a = __builtin_amdgcn_mfma_f32_16x16x32_bf16(af[2][mi], bf[0][ni], a, 0, 0, 0);
        acc[mi][ni] = a;
      }
    __syncthreads();
  }
  // ---- epilogue ----
#pragma unroll
  for (int ni = 0; ni < 4; ++ni) {
    const int n = bn + wn * 64 + ni * 16 + ln;
    const float bb = bias[n];
#pragma unroll
    for (int mi = 0; mi < 2; ++mi)
#pragma unroll
      for (int r = 0; r < 4; ++r) {
        const int m = bm + wm * 32 + mi * 16 + kq * 4 + r;
        C[(size_t)m * N + n] = fmaxf(__fadd_rn(acc[mi][ni][r], bb), 0.0f);
      }
  }
}

// ---------------------------------------------------------------------------
// Layer 3 split-bf16 MFMA + softplus: ALPHA ONLY (r4 4-wave version).
// ---------------------------------------------------------------------------
__global__ __launch_bounds__(256) void gemm3_alpha(
    const float* __restrict__ A, const unsigned short* __restrict__ BT,
    const float* __restrict__ bl, float* __restrict__ out) {
  constexpr int K = 512, N = 64;
  constexpr size_t PL = (size_t)N * K;  // 32768
  __shared__ unsigned short As[3][64 * 32];
  __shared__ unsigned short Bs[3][64 * 32];
  const int t = threadIdx.x;
  const int lane = t & 63, w = t >> 6;
  const int ln = lane & 15, kq = lane >> 4;
  const int bm = blockIdx.x * 64;
  const int rq = kq ^ ((ln >> 1) & 3);
  const int kcs = ((lane & 3) ^ ((lane >> 3) & 3)) * 8;

  floatx4 acc[4];
#pragma unroll
  for (int j = 0; j < 4; ++j) acc[j] = (floatx4)0.0f;

  for (int k0 = 0; k0 < K; k0 += 32) {
#pragma unroll
    for (int p = 0; p < 3; ++p) {
      const int n = w * 16 + (lane >> 2);
      const unsigned short* g = BT + p * PL + (size_t)n * K + (k0 + kcs);
      __builtin_amdgcn_global_load_lds(
          (const __attribute__((address_space(1))) unsigned int*)g,
          (__attribute__((address_space(3))) unsigned int*)&Bs[p][w * 512],
          16, 0, 0);
    }
#pragma unroll
    for (int it = 0; it < 2; ++it) {
      const int e4 = (it * 256 + t) * 4;
      const int m = e4 >> 5, kc = e4 & 31;
      const float4 q = *reinterpret_cast<const float4*>(
          &A[(size_t)(bm + m) * K + (k0 + kc)]);
      ushort4 h, l, l2;
      split3(q.x, h.x, l.x, l2.x);
      split3(q.y, h.y, l.y, l2.y);
      split3(q.z, h.z, l.z, l2.z);
      split3(q.w, h.w, l.w, l2.w);
      const int si = m * 32 + (((kc >> 3) ^ ((m >> 1) & 3)) << 3) + (kc & 7);
      *reinterpret_cast<ushort4*>(&As[0][si]) = h;
      *reinterpret_cast<ushort4*>(&As[1][si]) = l;
      *reinterpret_cast<ushort4*>(&As[2][si]) = l2;
    }
    __syncthreads();
    short8 af[3];
#pragma unroll
    for (int p = 0; p < 3; ++p)
      af[p] = *reinterpret_cast<const short8*>(
          &As[p][(w * 16 + ln) * 32 + rq * 8]);
#pragma unroll
    for (int ni = 0; ni < 4; ++ni) {
      const short8 b0 = *reinterpret_cast<const short8*>(
          &Bs[0][(ni * 16 + ln) * 32 + rq * 8]);
      const short8 b1 = *reinterpret_cast<const short8*>(
          &Bs[1][(ni * 16 + ln) * 32 + rq * 8]);
      const short8 b2 = *reinterpret_cast<const short8*>(
          &Bs[2][(ni * 16 + ln) * 32 + rq * 8]);
      floatx4 a = acc[ni];
      a = __builtin_amdgcn_mfma_f32_16x16x32_bf16(af[0], b0, a, 0, 0, 0);
      a = __builtin_amdgcn_mfma_f32_16x16x32_bf16(af[0], b1, a, 0, 0, 0);
      a = __builtin_amdgcn_mfma_f32_16x16x32_bf16(af[1], b0, a, 0, 0, 0);
      a = __builtin_amdgcn_mfma_f32_16x16x32_bf16(af[1], b1, a, 0, 0, 0);
      a = __builtin_amdgcn_mfma_f32_16x16x32_bf16(af[0], b2, a, 0, 0, 0);
      a = __builtin_amdgcn_mfma_f32_16x16x32_bf16(af[2], b0, a, 0, 0, 0);
      acc[ni] = a;
    }
    __syncthreads();
  }
#pragma unroll
  for (int ni = 0; ni < 4; ++ni) {
    const int n = ni * 16 + ln;
    const float bb = bl[n];
#pragma unroll
    for (int r = 0; r < 4; ++r) {
      const int m = bm + w * 16 + kq * 4 + r;
      const float x = __fadd_rn(acc[ni][r], bb);
      const float sp = __fadd_rn(fmaxf(x, 0.0f), log1pf(expf(-fabsf(x))));
      out[(size_t)m * 64 + n] = __fadd_rn(sp, 0.5f);
    }
  }
}

// ---------------------------------------------------------------------------
// Standalone gamma sampler: 2M elements, 4 per thread, float4 coalesced.
// ---------------------------------------------------------------------------
__global__ __launch_bounds__(256) void gamma_kernel(
    const float* __restrict__ alpha, float* __restrict__ smp,
    uint32_t kz0, uint32_t kz1, uint32_t ku0, uint32_t ku1) {
  const uint32_t i4 = ((uint32_t)blockIdx.x * 256u + (uint32_t)threadIdx.x) * 4u;
  const float4 a = *reinterpret_cast<const float4*>(&alpha[i4]);
  float4 s;
  s.x = gamma_sample(a.x, i4 + 0u, kz0, kz1, ku0, ku1);
  s.y = gamma_sample(a.y, i4 + 1u, kz0, kz1, ku0, ku1);
  s.z = gamma_sample(a.z, i4 + 2u, kz0, kz1, ku0, ku1);
  s.w = gamma_sample(a.w, i4 + 3u, kz0, kz1, ku0, ku1);
  *reinterpret_cast<float4*>(&smp[i4]) = s;
}

// ---------------------------------------------------------------------------
extern "C" void kernel_launch(void* const* d_in, const int* in_sizes, int n_in,
                              void* d_out, int out_size, void* d_ws, size_t ws_size,
                              hipStream_t stream) {
  (void)in_sizes; (void)n_in; (void)out_size; (void)ws_size;
  const float* x  = (const float*)d_in[0];
  const float* W0 = (const float*)d_in[1];
  const float* b0 = (const float*)d_in[2];
  const float* W1 = (const float*)d_in[3];
  const float* b1 = (const float*)d_in[4];
  const float* Wl = (const float*)d_in[5];
  const float* bl = (const float*)d_in[6];
  float* h1 = (float*)d_ws;                      // 32768x512 f32 = 64 MiB
  float* h2 = h1 + (size_t)MDIM * HDIM;          // 64 MiB
  float* out = (float*)d_out;                    // [alpha | sample], f32

  // d_out doubles as early scratch for the pre-split transposed W planes
  // (consumed by gemm1/gemm2, then overwritten by gemm3_alpha/gamma_kernel).
  unsigned short* W0T = (unsigned short*)out;           // 3 MiB in alpha region
  unsigned short* W1T = (unsigned short*)(out + BL);    // 1.5 MiB in sample region
  // WlT goes into the h1 region AFTER gemm2 has consumed h1 (stream-ordered).
  unsigned short* WlT = (unsigned short*)d_ws;          // 192 KiB, dead-h1 reuse

  // jax.random.split(jax.random.key(1)) under jax_threefry_partitionable.
  uint32_t kz0, kz1, ku0, ku1;
  tf2x32(0u, 1u, 0u, 0u, kz0, kz1);
  tf2x32(0u, 1u, 0u, 1u, ku0, ku1);

  split_transpose<<<dim3((DIN / 32) * (HDIM / 32)), 256, 0, stream>>>(
      W0, W0T, DIN, HDIM);
  split_transpose<<<dim3((HDIM / 32) * (HDIM / 32)), 256, 0, stream>>>(
      W1, W1T, HDIM, HDIM);

  gemm1_k1024<<<dim3(HDIM / 128, MDIM / 128), 256, 0, stream>>>(x, W0T, b0, h1);
  gemm2_k512<<<dim3(HDIM / 128, MDIM / 64), 256, 0, stream>>>(h1, W1T, b1, h2);

  split_transpose<<<dim3((HDIM / 32) * (LDIM / 32)), 256, 0, stream>>>(
      Wl, WlT, HDIM, LDIM);

  gemm3_alpha<<<dim3(MDIM / 64), 256, 0, stream>>>(h2, WlT, bl, out);

  // alpha region of d_out is complete; sample from it.
  gamma_kernel<<<dim3(BL / 1024), 256, 0, stream>>>(out, out + BL,
                                                    kz0, kz1, ku0, ku1);
}